// Round 5
// baseline (19559.937 us; speedup 1.0000x reference)
//
#include <hip/hip_runtime.h>
#include <hip/hip_bf16.h>
#include <math.h>

// ---------------------------------------------------------------------------
// MyRNN persistent kernel, round 5: tagged-chunk direct broadcast.
//   Phase A: xp = x@Wx^T + bx (unchanged; WG-private, barrier-free).
//   Phase B: 2048 steps. Wave wv of WG w owns hidden row 16w+wv (Wh row in
//     VGPRs). Publish: lane0 stores ONE 4B word ((t+1)<<16 | bf16(h)) --
//     self-validating, fire-and-forget (no drain, no seq, no tree, no go).
//     Consume: wave wv optimistically loads the 16 records of group wv
//     (4 tagged words/lane via 2x8B atomic loads), validates tag==t,
//     sleep-backoff on miss. LDS h double-buffer -> ONE barrier per step.
//   Phase C: out = sigmoid(hT @ Wo^T + bo).
//
// ws layout (32-bit words):
//   [1024,5120)  hb0: 256 records x 16 tagged words (16 KiB) - even steps
//   [5120,9216)  hb1: same, odd steps
//   [12288,...)  xp [256][2048][16] f32 (32 MiB)
// words [0,9216) memset to 0 every launch: tag0 + h0=0 (deterministic replay).
// ---------------------------------------------------------------------------

#define T_STEPS  2048
#define INPUT_N  2048
#define HIDDEN_N 4096
#define NWG      256
#define NTHR     1024

typedef float f32x4 __attribute__((ext_vector_type(4)));
typedef unsigned int uint32;
typedef unsigned long long u64;

__device__ __forceinline__ float wave_reduce(float v) {
#pragma unroll
  for (int off = 32; off > 0; off >>= 1) v += __shfl_xor(v, off, 64);
  return v;
}

__device__ __forceinline__ float bits_to_f(uint32 u) {
  union { uint32 u; float f; } c; c.u = u; return c.f;
}

__global__ __attribute__((amdgpu_flat_work_group_size(1024, 1024)))
__attribute__((amdgpu_waves_per_eu(4, 4))) void rnn_persistent(
    const float* __restrict__ x,
    const float* __restrict__ wh_w, const float* __restrict__ wh_b,
    const float* __restrict__ wx_w, const float* __restrict__ wx_b,
    const float* __restrict__ wo_w, const float* __restrict__ wo_b,
    float* __restrict__ out, float* __restrict__ ws) {
  const int w    = blockIdx.x;    // owns hidden rows [16w, 16w+16)
  const int tid  = threadIdx.x;
  const int lane = tid & 63;
  const int wv   = tid >> 6;      // wave 0..15; also the group it monitors

  uint32* hb0 = (uint32*)(ws + 1024);   // 4096 tagged words
  uint32* hb1 = (uint32*)(ws + 5120);
  float*  xp  = ws + 12288;             // [w][t][16]

  __shared__ float s_h[2][HIDDEN_N];    // 32 KiB double-buffered staged h

  // ------------------ Phase A: xp (barrier-free, reduce-free) --------------
  {
    const int tq = lane >> 4;        // 0..3
    const int r  = lane & 15;        // row within WG slice
    const float* wrow = wx_w + (size_t)(w * 16 + r) * INPUT_N;
    const float  bA   = wx_b[w * 16 + r];
    for (int g = wv; g < 64; g += 16) {       // 4 groups per wave
      const int t0 = g * 32 + tq;             // t = t0 + 4j, j<8
      f32x4 acc[8];
      const float* xr[8];
#pragma unroll
      for (int j = 0; j < 8; ++j) {
        acc[j] = (f32x4){0.f, 0.f, 0.f, 0.f};
        xr[j]  = x + (size_t)(t0 + 4 * j) * INPUT_N;
      }
      for (int k = 0; k < 512; ++k) {         // 16B granules over K=2048
        f32x4 wq = *(const f32x4*)(wrow + (size_t)k * 4);
#pragma unroll
        for (int j = 0; j < 8; ++j)
          acc[j] += (*(const f32x4*)(xr[j] + (size_t)k * 4)) * wq;
      }
#pragma unroll
      for (int j = 0; j < 8; ++j) {
        float s = acc[j].x + acc[j].y + acc[j].z + acc[j].w + bA;
        xp[((size_t)w * T_STEPS + (t0 + 4 * j)) * 16 + r] = s;
      }
    }
  }
  __syncthreads();   // xp slice complete (WG-private, same CU)

  // ------------------ Phase B: the scan ------------------------------------
  const float* whrow = wh_w + (size_t)(w * 16 + wv) * HIDDEN_N + lane * 4;
  f32x4 W[16];
#pragma unroll
  for (int i = 0; i < 16; ++i) W[i] = *(const f32x4*)(whrow + i * 256);
  const float bB = wh_b[w * 16 + wv];
  const int   cbase = wv * 256 + 4 * lane;   // my 4 chunks within a buffer
  const int   pidx  = w * 16 + wv;           // my publish word index

  for (int t = 0; t < T_STEPS; ++t) {
    // prefetch xp[t][wv] (uniform per wave, WG-private, latency hidden)
    const float xpv = xp[((size_t)w * T_STEPS + t) * 16 + wv];

    // 1) optimistic tagged-load of my 4 chunks of h_t; validate tag==t
    const uint32* src = ((t & 1) ? hb1 : hb0) + cbase;
    const uint32  tgt = (uint32)t;
    u64 u01, u23;
    for (;;) {
      u01 = __hip_atomic_load((const u64*)src, __ATOMIC_RELAXED,
                              __HIP_MEMORY_SCOPE_AGENT);
      u23 = __hip_atomic_load((const u64*)(src + 2), __ATOMIC_RELAXED,
                              __HIP_MEMORY_SCOPE_AGENT);
      bool ok = (((uint32)u01 >> 16) == tgt) &
                (((uint32)(u01 >> 32) >> 16) == tgt) &
                (((uint32)u23 >> 16) == tgt) &
                (((uint32)(u23 >> 32) >> 16) == tgt);
      if (__all(ok)) break;
      __builtin_amdgcn_s_sleep(4);
    }
    {
      float* dst = &s_h[t & 1][cbase];
      dst[0] = bits_to_f((uint32)u01 << 16);
      dst[1] = bits_to_f((uint32)(u01 >> 32) << 16);
      dst[2] = bits_to_f((uint32)u23 << 16);
      dst[3] = bits_to_f((uint32)(u23 >> 32) << 16);
    }
    __syncthreads();   // all 4096 values staged (single barrier per step)

    // 2) full-row dot from LDS against resident W
    const float* hl = &s_h[t & 1][0];
    f32x4 a0 = {0.f, 0.f, 0.f, 0.f}, a1 = {0.f, 0.f, 0.f, 0.f};
#pragma unroll
    for (int i = 0; i < 16; i += 2) {
      a0 += (*(const f32x4*)&hl[lane * 4 + i * 256]) * W[i];
      a1 += (*(const f32x4*)&hl[lane * 4 + (i + 1) * 256]) * W[i + 1];
    }
    float d = wave_reduce(a0.x + a0.y + a0.z + a0.w +
                          a1.x + a1.y + a1.z + a1.w);

    // 3) lane0: tanh -> tagged bf16 word -> fire-and-forget publish
    if (lane == 0) {
      float hn = tanhf(d + bB + xpv);
      __hip_bfloat16 b = __float2bfloat16(hn);
      uint32 word = ((uint32)(t + 1) << 16) | (uint32)(*(unsigned short*)&b);
      uint32* pdst = ((t & 1) ? hb0 : hb1) + pidx;   // h_{t+1} buffer
      __hip_atomic_store(pdst, word, __ATOMIC_RELAXED,
                         __HIP_MEMORY_SCOPE_AGENT);
    }
  }

  // ------------------ Phase C: output --------------------------------------
  {
    const uint32* src = hb0 + cbase;     // h_2048 (tag 2048) in hb[2048&1]=hb0
    const uint32  tgt = (uint32)T_STEPS;
    u64 u01, u23;
    for (;;) {
      u01 = __hip_atomic_load((const u64*)src, __ATOMIC_RELAXED,
                              __HIP_MEMORY_SCOPE_AGENT);
      u23 = __hip_atomic_load((const u64*)(src + 2), __ATOMIC_RELAXED,
                              __HIP_MEMORY_SCOPE_AGENT);
      bool ok = (((uint32)u01 >> 16) == tgt) &
                (((uint32)(u01 >> 32) >> 16) == tgt) &
                (((uint32)u23 >> 16) == tgt) &
                (((uint32)(u23 >> 32) >> 16) == tgt);
      if (__all(ok)) break;
      __builtin_amdgcn_s_sleep(4);
    }
    float* dst = &s_h[0][cbase];
    dst[0] = bits_to_f((uint32)u01 << 16);
    dst[1] = bits_to_f((uint32)(u01 >> 32) << 16);
    dst[2] = bits_to_f((uint32)u23 << 16);
    dst[3] = bits_to_f((uint32)(u23 >> 32) << 16);
  }
  __syncthreads();
  if (wv < 8) {
    const int o = w * 8 + wv;
    const float* worow = wo_w + (size_t)o * HIDDEN_N + lane * 4;
    f32x4 acc = {0.f, 0.f, 0.f, 0.f};
#pragma unroll
    for (int k = 0; k < 16; ++k)
      acc += (*(const f32x4*)(worow + k * 256)) *
             (*(const f32x4*)&s_h[0][lane * 4 + k * 256]);
    float s = wave_reduce(acc.x + acc.y + acc.z + acc.w);
    if (lane == 0) {
      float z = s + wo_b[o];
      out[o] = 1.f / (1.f + expf(-z));
    }
  }
}

extern "C" void kernel_launch(void* const* d_in, const int* in_sizes, int n_in,
                              void* d_out, int out_size, void* d_ws,
                              size_t ws_size, hipStream_t stream) {
  const float* x    = (const float*)d_in[0];
  const float* wh_w = (const float*)d_in[1];
  const float* wh_b = (const float*)d_in[2];
  const float* wx_w = (const float*)d_in[3];
  const float* wx_b = (const float*)d_in[4];
  const float* wo_w = (const float*)d_in[5];
  const float* wo_b = (const float*)d_in[6];
  float* out = (float*)d_out;
  float* ws  = (float*)d_ws;

  // tagged h buffers zeroed every call: tag0 <=> h_0 = 0 (deterministic)
  hipMemsetAsync(d_ws, 0, 9216 * 4, stream);

  hipLaunchKernelGGL(rnn_persistent, dim3(NWG), dim3(NTHR), 0, stream,
                     x, wh_w, wh_b, wx_w, wx_b, wo_w, wo_b, out, ws);
}

// Round 6
// 14321.924 us; speedup vs baseline: 1.3657x; 1.3657x over previous
//
#include <hip/hip_runtime.h>
#include <hip/hip_bf16.h>
#include <math.h>

// ---------------------------------------------------------------------------
// MyRNN persistent kernel, round 6: tagged data + LDS-counted arrival + single
// root counter poll (one write-per-WG line; r3-proven poll rate).
//   Phase A: xp = x@Wx^T + bx (unchanged; WG-private, barrier-free).
//   Phase B: per step:
//     barrier1 (wave0 first polls root >= 256*t)
//     all waves: stage own slice of tagged h_t, validate tag==t (rarely spins)
//     barrier2; dot(own row) from LDS vs resident Wh; reduce; lane0: tanh ->
//     single tagged 4B store (fire-and-forget) -> LDS ds_add; 16th wave ->
//     atomicAdd(root, 1).
//   Phase C: out = sigmoid(hT @ Wo^T + bo).
//
// ws layout (32-bit words):
//   [0]          root arrival counter (monotone, 256 adds/step)
//   [1024,5120)  hb0: 4096 tagged words ((t)<<16 | bf16) - h for even t
//   [5120,9216)  hb1: same, odd t
//   [12288,...)  xp [256][2048][16] f32 (32 MiB)
// words [0,9216) memset 0 every launch: root=0, tag0 <=> h_0=0 (deterministic).
// ---------------------------------------------------------------------------

#define T_STEPS  2048
#define INPUT_N  2048
#define HIDDEN_N 4096
#define NWG      256
#define NTHR     1024

typedef float f32x4 __attribute__((ext_vector_type(4)));
typedef unsigned int uint32;
typedef unsigned long long u64;

__device__ __forceinline__ float wave_reduce(float v) {
#pragma unroll
  for (int off = 32; off > 0; off >>= 1) v += __shfl_xor(v, off, 64);
  return v;
}

__device__ __forceinline__ float bits_to_f(uint32 u) {
  union { uint32 u; float f; } c; c.u = u; return c.f;
}

__global__ __attribute__((amdgpu_flat_work_group_size(1024, 1024)))
__attribute__((amdgpu_waves_per_eu(4, 4))) void rnn_persistent(
    const float* __restrict__ x,
    const float* __restrict__ wh_w, const float* __restrict__ wh_b,
    const float* __restrict__ wx_w, const float* __restrict__ wx_b,
    const float* __restrict__ wo_w, const float* __restrict__ wo_b,
    float* __restrict__ out, float* __restrict__ ws) {
  const int w    = blockIdx.x;    // owns hidden rows [16w, 16w+16)
  const int tid  = threadIdx.x;
  const int lane = tid & 63;
  const int wv   = tid >> 6;      // wave 0..15 owns row 16w+wv

  int*    root = (int*)ws;
  uint32* hb0  = (uint32*)(ws + 1024);   // 4096 tagged words
  uint32* hb1  = (uint32*)(ws + 5120);
  float*  xp   = ws + 12288;             // [w][t][16]

  __shared__ float s_h[HIDDEN_N];   // 16 KiB staged h (f32)
  __shared__ int   s_cnt;           // per-WG arrival count (monotone)

  // ------------------ Phase A: xp (barrier-free, reduce-free) --------------
  {
    const int tq = lane >> 4;        // 0..3
    const int r  = lane & 15;        // row within WG slice
    const float* wrow = wx_w + (size_t)(w * 16 + r) * INPUT_N;
    const float  bA   = wx_b[w * 16 + r];
    for (int g = wv; g < 64; g += 16) {       // 4 groups per wave
      const int t0 = g * 32 + tq;             // t = t0 + 4j, j<8
      f32x4 acc[8];
      const float* xr[8];
#pragma unroll
      for (int j = 0; j < 8; ++j) {
        acc[j] = (f32x4){0.f, 0.f, 0.f, 0.f};
        xr[j]  = x + (size_t)(t0 + 4 * j) * INPUT_N;
      }
      for (int k = 0; k < 512; ++k) {         // 16B granules over K=2048
        f32x4 wq = *(const f32x4*)(wrow + (size_t)k * 4);
#pragma unroll
        for (int j = 0; j < 8; ++j)
          acc[j] += (*(const f32x4*)(xr[j] + (size_t)k * 4)) * wq;
      }
#pragma unroll
      for (int j = 0; j < 8; ++j) {
        float s = acc[j].x + acc[j].y + acc[j].z + acc[j].w + bA;
        xp[((size_t)w * T_STEPS + (t0 + 4 * j)) * 16 + r] = s;
      }
    }
  }
  if (tid == 0) s_cnt = 0;
  __syncthreads();   // xp slice complete; s_cnt init

  // ------------------ Phase B: the scan ------------------------------------
  const float* whrow = wh_w + (size_t)(w * 16 + wv) * HIDDEN_N + lane * 4;
  f32x4 W[16];
#pragma unroll
  for (int i = 0; i < 16; ++i) W[i] = *(const f32x4*)(whrow + i * 256);
  const float bB = wh_b[w * 16 + wv];
  const int   cbase = wv * 256 + 4 * lane;   // my 4 staged words
  const int   pidx  = w * 16 + wv;           // my publish word

  for (int t = 0; t < T_STEPS; ++t) {
    // prefetch xp[t][wv] (uniform per wave, WG-private, latency hidden)
    const float xpv = xp[((size_t)w * T_STEPS + t) * 16 + wv];

    // 1) wave0 polls the root counter: all 256 WGs published h_t
    if (wv == 0 && t > 0) {
      const int target = 256 * t;
      while (__hip_atomic_load(root, __ATOMIC_RELAXED,
                               __HIP_MEMORY_SCOPE_AGENT) < target)
        __builtin_amdgcn_s_sleep(1);
    }
    __syncthreads();   // barrier1: all waves past dot of t-1; root seen

    // 2) stage my 4 tagged words of h_t; tags validate (rarely spins)
    {
      const uint32* src = ((t & 1) ? hb1 : hb0) + cbase;
      const uint32  tgt = (uint32)t;
      u64 u01, u23;
      for (;;) {
        u01 = __hip_atomic_load((const u64*)src, __ATOMIC_RELAXED,
                                __HIP_MEMORY_SCOPE_AGENT);
        u23 = __hip_atomic_load((const u64*)(src + 2), __ATOMIC_RELAXED,
                                __HIP_MEMORY_SCOPE_AGENT);
        bool ok = (((uint32)u01 >> 16) == tgt) &
                  (((uint32)(u01 >> 32) >> 16) == tgt) &
                  (((uint32)u23 >> 16) == tgt) &
                  (((uint32)(u23 >> 32) >> 16) == tgt);
        if (__all(ok)) break;   // only spins in the add-overtook-data window
      }
      f32x4 p;
      p.x = bits_to_f((uint32)u01 << 16);
      p.y = bits_to_f((uint32)(u01 >> 32) << 16);
      p.z = bits_to_f((uint32)u23 << 16);
      p.w = bits_to_f((uint32)(u23 >> 32) << 16);
      *(f32x4*)&s_h[cbase] = p;
    }
    __syncthreads();   // barrier2: s_h complete

    // 3) own-row dot from LDS against resident W
    f32x4 a0 = {0.f, 0.f, 0.f, 0.f}, a1 = {0.f, 0.f, 0.f, 0.f};
#pragma unroll
    for (int i = 0; i < 16; i += 2) {
      a0 += (*(const f32x4*)&s_h[lane * 4 + i * 256]) * W[i];
      a1 += (*(const f32x4*)&s_h[lane * 4 + (i + 1) * 256]) * W[i + 1];
    }
    float d = wave_reduce(a0.x + a0.y + a0.z + a0.w +
                          a1.x + a1.y + a1.z + a1.w);

    // 4) lane0: tanh -> tagged publish -> arrival count
    if (lane == 0) {
      float hn = tanhf(d + bB + xpv);
      __hip_bfloat16 b = __float2bfloat16(hn);
      uint32 word = ((uint32)(t + 1) << 16) | (uint32)(*(unsigned short*)&b);
      uint32* pdst = ((t & 1) ? hb0 : hb1) + pidx;   // h_{t+1} buffer
      __hip_atomic_store(pdst, word, __ATOMIC_RELAXED,
                         __HIP_MEMORY_SCOPE_AGENT);   // fire-and-forget
      int old = atomicAdd(&s_cnt, 1);                 // LDS, ~30cy
      if (old == 16 * (t + 1) - 1)                    // WG's 16th arrival
        __hip_atomic_fetch_add(root, 1, __ATOMIC_RELAXED,
                               __HIP_MEMORY_SCOPE_AGENT);
    }
  }

  // ------------------ Phase C: output --------------------------------------
  if (wv == 0) {
    const int target = 256 * T_STEPS;
    while (__hip_atomic_load(root, __ATOMIC_RELAXED,
                             __HIP_MEMORY_SCOPE_AGENT) < target)
      __builtin_amdgcn_s_sleep(1);
  }
  __syncthreads();
  {
    const uint32* src = hb0 + cbase;   // h_2048 (tag 2048) in hb[2048&1]=hb0
    const uint32  tgt = (uint32)T_STEPS;
    u64 u01, u23;
    for (;;) {
      u01 = __hip_atomic_load((const u64*)src, __ATOMIC_RELAXED,
                              __HIP_MEMORY_SCOPE_AGENT);
      u23 = __hip_atomic_load((const u64*)(src + 2), __ATOMIC_RELAXED,
                              __HIP_MEMORY_SCOPE_AGENT);
      bool ok = (((uint32)u01 >> 16) == tgt) &
                (((uint32)(u01 >> 32) >> 16) == tgt) &
                (((uint32)u23 >> 16) == tgt) &
                (((uint32)(u23 >> 32) >> 16) == tgt);
      if (__all(ok)) break;
    }
    f32x4 p;
    p.x = bits_to_f((uint32)u01 << 16);
    p.y = bits_to_f((uint32)(u01 >> 32) << 16);
    p.z = bits_to_f((uint32)u23 << 16);
    p.w = bits_to_f((uint32)(u23 >> 32) << 16);
    *(f32x4*)&s_h[cbase] = p;
  }
  __syncthreads();
  if (wv < 8) {
    const int o = w * 8 + wv;
    const float* worow = wo_w + (size_t)o * HIDDEN_N + lane * 4;
    f32x4 acc = {0.f, 0.f, 0.f, 0.f};
#pragma unroll
    for (int k = 0; k < 16; ++k)
      acc += (*(const f32x4*)(worow + k * 256)) *
             (*(const f32x4*)&s_h[lane * 4 + k * 256]);
    float s = wave_reduce(acc.x + acc.y + acc.z + acc.w);
    if (lane == 0) {
      float z = s + wo_b[o];
      out[o] = 1.f / (1.f + expf(-z));
    }
  }
}

extern "C" void kernel_launch(void* const* d_in, const int* in_sizes, int n_in,
                              void* d_out, int out_size, void* d_ws,
                              size_t ws_size, hipStream_t stream) {
  const float* x    = (const float*)d_in[0];
  const float* wh_w = (const float*)d_in[1];
  const float* wh_b = (const float*)d_in[2];
  const float* wx_w = (const float*)d_in[3];
  const float* wx_b = (const float*)d_in[4];
  const float* wo_w = (const float*)d_in[5];
  const float* wo_b = (const float*)d_in[6];
  float* out = (float*)d_out;
  float* ws  = (float*)d_ws;

  // root + tagged h buffers zeroed every call (tag0 <=> h_0 = 0)
  hipMemsetAsync(d_ws, 0, 9216 * 4, stream);

  hipLaunchKernelGGL(rnn_persistent, dim3(NWG), dim3(NTHR), 0, stream,
                     x, wh_w, wh_b, wx_w, wx_b, wo_w, wo_b, out, ws);
}

// Round 7
// 9577.642 us; speedup vs baseline: 2.0422x; 1.4953x over previous
//
#include <hip/hip_runtime.h>
#include <hip/hip_bf16.h>
#include <math.h>

// ---------------------------------------------------------------------------
// MyRNN persistent kernel, round 7: r3's tree skeleton, hops minimized.
//   publish: per-wave lane0 fires ONE tagged 4B word ((t+1)<<16 | bf16(h)),
//            no drain (tags self-validate); LDS ds_add arrival count;
//            16th wave -> grp[w>>4] RMW (16 lines x 16 RMW);
//            grp-last -> root RMW; root-last -> 8 go mirrors.
//   wait:    wave0 polls go mirror (w>>5) -- write-once-per-step line,
//            32 pollers/line, no sleep.
//   stage:   16B/lane tagged load, validate tag==t (rare spin in the
//            add-overtook-data window only).
//
// ws layout (32-bit words):
//   [0,256)      grp[g] at word g*16 (16 separate lines)
//   [256]        root counter
//   [320,448)    go mirrors: go_m[m] at word 320+m*16 (8 lines)
//   [1024,5120)  hb0: 4096 tagged words - h for even t
//   [5120,9216)  hb1: same, odd t
//   [12288,...)  xp [256][2048][16] f32 (32 MiB)
// words [0,9216) memset 0 every launch: counters=0, tag0 <=> h_0=0.
// ---------------------------------------------------------------------------

#define T_STEPS  2048
#define INPUT_N  2048
#define HIDDEN_N 4096
#define NWG      256
#define NTHR     1024

typedef float f32x4 __attribute__((ext_vector_type(4)));
typedef unsigned int uint32;
typedef unsigned long long u64;

__device__ __forceinline__ float wave_reduce(float v) {
#pragma unroll
  for (int off = 32; off > 0; off >>= 1) v += __shfl_xor(v, off, 64);
  return v;
}

__device__ __forceinline__ float bits_to_f(uint32 u) {
  union { uint32 u; float f; } c; c.u = u; return c.f;
}

__global__ __attribute__((amdgpu_flat_work_group_size(1024, 1024)))
__attribute__((amdgpu_waves_per_eu(4, 4))) void rnn_persistent(
    const float* __restrict__ x,
    const float* __restrict__ wh_w, const float* __restrict__ wh_b,
    const float* __restrict__ wx_w, const float* __restrict__ wx_b,
    const float* __restrict__ wo_w, const float* __restrict__ wo_b,
    float* __restrict__ out, float* __restrict__ ws) {
  const int w    = blockIdx.x;    // owns hidden rows [16w, 16w+16)
  const int tid  = threadIdx.x;
  const int lane = tid & 63;
  const int wv   = tid >> 6;      // wave 0..15 owns row 16w+wv

  int*    grp  = (int*)ws;               // grp[g] at word g*16
  int*    root = (int*)ws + 256;
  int*    gom  = (int*)ws + 320;         // go_m[m] at word m*16
  uint32* hb0  = (uint32*)(ws + 1024);   // 4096 tagged words
  uint32* hb1  = (uint32*)(ws + 5120);
  float*  xp   = ws + 12288;             // [w][t][16]

  int* mygo = gom + ((w >> 5) << 4);     // this WG's go mirror

  __shared__ float s_h[HIDDEN_N];   // 16 KiB staged h (f32)
  __shared__ int   s_cnt;           // per-WG arrival count (monotone)

  // ------------------ Phase A: xp (barrier-free, reduce-free) --------------
  {
    const int tq = lane >> 4;        // 0..3
    const int r  = lane & 15;        // row within WG slice
    const float* wrow = wx_w + (size_t)(w * 16 + r) * INPUT_N;
    const float  bA   = wx_b[w * 16 + r];
    for (int g = wv; g < 64; g += 16) {       // 4 groups per wave
      const int t0 = g * 32 + tq;             // t = t0 + 4j, j<8
      f32x4 acc[8];
      const float* xr[8];
#pragma unroll
      for (int j = 0; j < 8; ++j) {
        acc[j] = (f32x4){0.f, 0.f, 0.f, 0.f};
        xr[j]  = x + (size_t)(t0 + 4 * j) * INPUT_N;
      }
      for (int k = 0; k < 512; ++k) {         // 16B granules over K=2048
        f32x4 wq = *(const f32x4*)(wrow + (size_t)k * 4);
#pragma unroll
        for (int j = 0; j < 8; ++j)
          acc[j] += (*(const f32x4*)(xr[j] + (size_t)k * 4)) * wq;
      }
#pragma unroll
      for (int j = 0; j < 8; ++j) {
        float s = acc[j].x + acc[j].y + acc[j].z + acc[j].w + bA;
        xp[((size_t)w * T_STEPS + (t0 + 4 * j)) * 16 + r] = s;
      }
    }
  }
  if (tid == 0) s_cnt = 0;
  __syncthreads();   // xp slice complete; s_cnt init

  // ------------------ Phase B: the scan ------------------------------------
  const float* whrow = wh_w + (size_t)(w * 16 + wv) * HIDDEN_N + lane * 4;
  f32x4 W[16];
#pragma unroll
  for (int i = 0; i < 16; ++i) W[i] = *(const f32x4*)(whrow + i * 256);
  const float bB = wh_b[w * 16 + wv];
  const int   cbase = wv * 256 + 4 * lane;   // my 4 staged words
  const int   pidx  = w * 16 + wv;           // my publish word
  const int   mygrp = (w >> 4) << 4;         // my grp counter word

  for (int t = 0; t < T_STEPS; ++t) {
    // prefetch xp[t][wv] (uniform per wave, WG-private, latency hidden)
    const float xpv = xp[((size_t)w * T_STEPS + t) * 16 + wv];

    // 1) wave0 polls this WG's go mirror (write-once-per-step line)
    if (wv == 0 && t > 0) {
      while (__hip_atomic_load(mygo, __ATOMIC_RELAXED,
                               __HIP_MEMORY_SCOPE_AGENT) < t) {}
    }
    __syncthreads();   // barrier1

    // 2) stage my 4 tagged words of h_t; validate (rare spin)
    {
      const uint32* src = ((t & 1) ? hb1 : hb0) + cbase;
      const uint32  tgt = (uint32)t;
      u64 u01, u23;
      for (;;) {
        u01 = __hip_atomic_load((const u64*)src, __ATOMIC_RELAXED,
                                __HIP_MEMORY_SCOPE_AGENT);
        u23 = __hip_atomic_load((const u64*)(src + 2), __ATOMIC_RELAXED,
                                __HIP_MEMORY_SCOPE_AGENT);
        bool ok = (((uint32)u01 >> 16) == tgt) &
                  (((uint32)(u01 >> 32) >> 16) == tgt) &
                  (((uint32)u23 >> 16) == tgt) &
                  (((uint32)(u23 >> 32) >> 16) == tgt);
        if (__all(ok)) break;   // spins only if adds overtook data stores
      }
      f32x4 p;
      p.x = bits_to_f((uint32)u01 << 16);
      p.y = bits_to_f((uint32)(u01 >> 32) << 16);
      p.z = bits_to_f((uint32)u23 << 16);
      p.w = bits_to_f((uint32)(u23 >> 32) << 16);
      *(f32x4*)&s_h[cbase] = p;
    }
    __syncthreads();   // barrier2: s_h complete

    // 3) own-row dot from LDS against resident W
    f32x4 a0 = {0.f, 0.f, 0.f, 0.f}, a1 = {0.f, 0.f, 0.f, 0.f};
#pragma unroll
    for (int i = 0; i < 16; i += 2) {
      a0 += (*(const f32x4*)&s_h[lane * 4 + i * 256]) * W[i];
      a1 += (*(const f32x4*)&s_h[lane * 4 + (i + 1) * 256]) * W[i + 1];
    }
    float d = wave_reduce(a0.x + a0.y + a0.z + a0.w +
                          a1.x + a1.y + a1.z + a1.w);

    // 4) lane0: tanh -> tagged publish -> arrival tree (no drains anywhere)
    if (lane == 0) {
      float hn = tanhf(d + bB + xpv);
      __hip_bfloat16 b = __float2bfloat16(hn);
      uint32 word = ((uint32)(t + 1) << 16) | (uint32)(*(unsigned short*)&b);
      uint32* pdst = ((t & 1) ? hb0 : hb1) + pidx;   // h_{t+1} buffer
      __hip_atomic_store(pdst, word, __ATOMIC_RELAXED,
                         __HIP_MEMORY_SCOPE_AGENT);   // fire-and-forget
      const int tcnt = 16 * (t + 1) - 1;
      int old = atomicAdd(&s_cnt, 1);                 // LDS, ~30cy
      if (old == tcnt) {                              // WG's 16th arrival
        int og = __hip_atomic_fetch_add(&grp[mygrp], 1, __ATOMIC_RELAXED,
                                        __HIP_MEMORY_SCOPE_AGENT);
        if (og == tcnt) {                             // group's 16th WG
          int orr = __hip_atomic_fetch_add(root, 1, __ATOMIC_RELAXED,
                                           __HIP_MEMORY_SCOPE_AGENT);
          if (orr == tcnt) {                          // 16th group
#pragma unroll
            for (int m = 0; m < 8; ++m)
              __hip_atomic_store(gom + m * 16, t + 1, __ATOMIC_RELAXED,
                                 __HIP_MEMORY_SCOPE_AGENT);
          }
        }
      }
    }
  }

  // ------------------ Phase C: output --------------------------------------
  if (wv == 0) {
    while (__hip_atomic_load(mygo, __ATOMIC_RELAXED,
                             __HIP_MEMORY_SCOPE_AGENT) < T_STEPS) {}
  }
  __syncthreads();
  {
    const uint32* src = hb0 + cbase;   // h_2048 (tag 2048) in hb[2048&1]=hb0
    const uint32  tgt = (uint32)T_STEPS;
    u64 u01, u23;
    for (;;) {
      u01 = __hip_atomic_load((const u64*)src, __ATOMIC_RELAXED,
                              __HIP_MEMORY_SCOPE_AGENT);
      u23 = __hip_atomic_load((const u64*)(src + 2), __ATOMIC_RELAXED,
                              __HIP_MEMORY_SCOPE_AGENT);
      bool ok = (((uint32)u01 >> 16) == tgt) &
                (((uint32)(u01 >> 32) >> 16) == tgt) &
                (((uint32)u23 >> 16) == tgt) &
                (((uint32)(u23 >> 32) >> 16) == tgt);
      if (__all(ok)) break;
    }
    f32x4 p;
    p.x = bits_to_f((uint32)u01 << 16);
    p.y = bits_to_f((uint32)(u01 >> 32) << 16);
    p.z = bits_to_f((uint32)u23 << 16);
    p.w = bits_to_f((uint32)(u23 >> 32) << 16);
    *(f32x4*)&s_h[cbase] = p;
  }
  __syncthreads();
  if (wv < 8) {
    const int o = w * 8 + wv;
    const float* worow = wo_w + (size_t)o * HIDDEN_N + lane * 4;
    f32x4 acc = {0.f, 0.f, 0.f, 0.f};
#pragma unroll
    for (int k = 0; k < 16; ++k)
      acc += (*(const f32x4*)(worow + k * 256)) *
             (*(const f32x4*)&s_h[lane * 4 + k * 256]);
    float s = wave_reduce(acc.x + acc.y + acc.z + acc.w);
    if (lane == 0) {
      float z = s + wo_b[o];
      out[o] = 1.f / (1.f + expf(-z));
    }
  }
}

extern "C" void kernel_launch(void* const* d_in, const int* in_sizes, int n_in,
                              void* d_out, int out_size, void* d_ws,
                              size_t ws_size, hipStream_t stream) {
  const float* x    = (const float*)d_in[0];
  const float* wh_w = (const float*)d_in[1];
  const float* wh_b = (const float*)d_in[2];
  const float* wx_w = (const float*)d_in[3];
  const float* wx_b = (const float*)d_in[4];
  const float* wo_w = (const float*)d_in[5];
  const float* wo_b = (const float*)d_in[6];
  float* out = (float*)d_out;
  float* ws  = (float*)d_ws;

  // counters + mirrors + tagged h buffers zeroed every call (tag0 <=> h_0=0)
  hipMemsetAsync(d_ws, 0, 9216 * 4, stream);

  hipLaunchKernelGGL(rnn_persistent, dim3(NWG), dim3(NTHR), 0, stream,
                     x, wh_w, wh_b, wx_w, wx_b, wo_w, wo_b, out, ws);
}